// Round 17
// baseline (128.044 us; speedup 1.0000x reference)
//
#include <hip/hip_runtime.h>
#include <hip/hip_bf16.h>

#define N_POS 4096
#define BH 16  // B * HEADS
#define JS 4   // j-slices: 2048 blocks = 8 blocks/CU, one fill round

typedef float f32x16 __attribute__((ext_vector_type(16)));
typedef short bf16x8 __attribute__((ext_vector_type(8)));

// fold attn scale (dim^-0.5 = 0.5) and log2(e) into q at pack time
#define QSCALE (0.5f * 1.44269504088896f)

__device__ __forceinline__ float fexp2(float x) {
#if __has_builtin(__builtin_amdgcn_exp2f)
    return __builtin_amdgcn_exp2f(x);
#else
    return exp2f(x);
#endif
}

__device__ __forceinline__ unsigned int bfbits(float f) {
    __hip_bfloat16 h = __float2bfloat16(f);
    return (unsigned int)*reinterpret_cast<unsigned short*>(&h);
}
__device__ __forceinline__ float bff32(unsigned int u) {
    unsigned int w = u << 16;
    float f;
    __builtin_memcpy(&f, &w, 4);
    return f;
}
__device__ __forceinline__ unsigned int pk2(unsigned int lo, unsigned int hi) {
    return lo | (hi << 16);
}

// ---------------- K1: qkv projection + MFMA fragment packing ----------------
// grid = 3 roles x 16 bh x 16 chunks = 768 blocks.
//  qfrag[bh][it][half][i&31]  : B-frag for QK  (half0=[qhi,qlo], half1=[qhi,0])
//  kfrag[bh][jt][half][j&31]  : A-frag for QK  (half0=[khi,khi], half1=[klo,0])
//   -> one 32x32x16 MFMA computes qhi*khi + qlo*khi + qhi*klo  (compensated dot)
//  vfrag[bh][step][vh][col][8]: B-frag for PV, col4 = ones (free l = sum(p))
__global__ __launch_bounds__(256) void qkv_pack(const float* __restrict__ x,
                                                const float* __restrict__ w_qkv,
                                                uint4* __restrict__ qfrag,
                                                uint4* __restrict__ kfrag,
                                                unsigned short* __restrict__ vfrag) {
    int blk = blockIdx.x;
    int role = blk >> 8;         // 0=q 1=k 2=v
    int bh = (blk >> 4) & 15;
    int chunk = blk & 15;
    int b = bh >> 2, h = bh & 3;
    int i = chunk * 256 + threadIdx.x;

    const float* xb = x + ((size_t)b * 64) * N_POS + i;
    const float* wr = w_qkv + (role * 16 + h * 4) * 64;   // wave-uniform rows

    float a[4] = {0, 0, 0, 0};
#pragma unroll 8
    for (int c = 0; c < 64; ++c) {
        float xv = xb[(size_t)c * N_POS];
#pragma unroll
        for (int d = 0; d < 4; ++d)
            a[d] = fmaf(wr[d * 64 + c], xv, a[d]);
    }

    int it = i >> 5, il = i & 31;
    size_t base = ((size_t)(bh * 128 + it) * 2) * 32 + il;

    if (role == 0) {
        unsigned int qh[4], ql[4];
#pragma unroll
        for (int d = 0; d < 4; ++d) {
            float qs = a[d] * QSCALE;
            qh[d] = bfbits(qs);
            ql[d] = bfbits(qs - bff32(qh[d]));
        }
        qfrag[base]      = make_uint4(pk2(qh[0], qh[1]), pk2(qh[2], qh[3]),
                                      pk2(ql[0], ql[1]), pk2(ql[2], ql[3]));
        qfrag[base + 32] = make_uint4(pk2(qh[0], qh[1]), pk2(qh[2], qh[3]), 0u, 0u);
    } else if (role == 1) {
        unsigned int kh[4], kl[4];
#pragma unroll
        for (int d = 0; d < 4; ++d) {
            kh[d] = bfbits(a[d]);
            kl[d] = bfbits(a[d] - bff32(kh[d]));
        }
        kfrag[base]      = make_uint4(pk2(kh[0], kh[1]), pk2(kh[2], kh[3]),
                                      pk2(kh[0], kh[1]), pk2(kh[2], kh[3]));
        kfrag[base + 32] = make_uint4(pk2(kl[0], kl[1]), pk2(kl[2], kl[3]), 0u, 0u);
    } else {
        // v transpose-pack: element (j&7) of entry [step=j>>4][vh=(j>>3)&1][col=d]
        int step = i >> 4, vh = (i >> 3) & 1, e = i & 7;
        size_t ventry = ((size_t)(bh * 256 + step) * 2 + vh) * 5;
#pragma unroll
        for (int d = 0; d < 4; ++d)
            vfrag[(ventry + d) * 8 + e] = (unsigned short)bfbits(a[d]);
        if (e == 0)  // ones column -> PV MFMA also produces l = sum_j p
            reinterpret_cast<uint4*>(vfrag)[ventry + 4] =
                make_uint4(0x3F803F80u, 0x3F803F80u, 0x3F803F80u, 0x3F803F80u);
    }
}

// ---------------- K2: MFMA flash attention partials ----------------
// wave = one 32-row i-tile x one j-slice (1024 j, JT=32). Same structure as
// r16 (40.5 us, VGPR 40): single acc, S-pipeline source shape (compiler may
// collapse it — measured benign), depth-2 K / depth-1 V prefetch, all-trans
// exp, setprio around PV. SINGLE CHANGE vs r16: lb(256,8) — at VGPR 40 the
// kernel fits the 64-reg cap with headroom (no spills -> the r11 spill-
// miscompile hazard doesn't apply), doubling resident waves to 8/SIMD.
__global__ __launch_bounds__(256, 8) void attn_mfma(const uint4* __restrict__ qfrag,
                                                    const uint4* __restrict__ kfrag,
                                                    const uint4* __restrict__ vfrag,
                                                    float* __restrict__ pacc,
                                                    float* __restrict__ pl) {
    constexpr int JT = 128 / JS;                 // 32 j-tiles per wave
    int wave = threadIdx.x >> 6;
    int lane = threadIdx.x & 63;
    int half = lane >> 5, c = lane & 31;
    int blk = blockIdx.x;                        // 16 bh * 32 itg * JS
    int js = blk & (JS - 1);
    int itg = (blk / JS) & 31;
    int bh = blk / (JS * 32);
    int it = itg * 4 + wave;

    uint4 qf_u = qfrag[((size_t)(bh * 128 + it) * 2 + half) * 32 + c];
    bf16x8 qf = __builtin_bit_cast(bf16x8, qf_u);

    const uint4* kp = kfrag + (size_t)bh * 128 * 64 + (size_t)js * JT * 64
                    + (size_t)half * 32 + c;
    int vcol = c < 4 ? c : 4;    // cols >4 read the ones column (result ignored)
    const uint4* vp = vfrag + (size_t)bh * 2560 + (size_t)js * JT * 20
                    + half * 5 + vcol;

    f32x16 acc, zc;
#pragma unroll
    for (int r = 0; r < 16; ++r) { acc[r] = 0.f; zc[r] = 0.f; }

    // pipeline prologue: QK for tile 0 in flight, K of tile 1 and V of tile 0 loaded
    uint4 kf_n = kp[0];
    uint4 v0_c = vp[0], v1_c = vp[10];
    f32x16 s_cur = __builtin_amdgcn_mfma_f32_32x32x16_bf16(
        __builtin_bit_cast(bf16x8, kf_n), qf, zc, 0, 0, 0);
    kf_n = kp[64];

#pragma unroll 2
    for (int jj = 0; jj < JT; ++jj) {
        // prefetch: K for tile jj+2, V for tile jj+1 (clamped at tail)
        int j2 = (jj + 2 < JT) ? jj + 2 : JT - 1;
        int j1 = (jj + 1 < JT) ? jj + 1 : JT - 1;
        uint4 kf_p = kp[j2 * 64];
        uint4 v0_n = vp[(2 * j1) * 10];
        uint4 v1_n = vp[(2 * j1 + 1) * 10];

        // issue QK for tile jj+1 — matrix pipe overlaps s_cur's softmax
        f32x16 s_next = __builtin_amdgcn_mfma_f32_32x32x16_bf16(
            __builtin_bit_cast(bf16x8, kf_n), qf, zc, 0, 0, 0);

        // softmax-process s_cur (tile jj)
        unsigned int t[8];
#pragma unroll
        for (int eo = 0; eo < 8; ++eo) {
            float plo = fexp2(s_cur[2 * eo]);
            float phi = fexp2(s_cur[2 * eo + 1]);
            unsigned int r_;
            asm("v_cvt_pk_bf16_f32 %0, %1, %2" : "=v"(r_) : "v"(plo), "v"(phi));
            t[eo] = r_;
        }
        // D-layout -> PV A-frag: swap upper half of t[a] with lower half of t[a+2]
        asm("v_permlane32_swap_b32 %0, %1" : "+v"(t[0]), "+v"(t[2]));
        asm("v_permlane32_swap_b32 %0, %1" : "+v"(t[1]), "+v"(t[3]));
        asm("v_permlane32_swap_b32 %0, %1" : "+v"(t[4]), "+v"(t[6]));
        asm("v_permlane32_swap_b32 %0, %1" : "+v"(t[5]), "+v"(t[7]));
        bf16x8 pa0 = __builtin_bit_cast(bf16x8, make_uint4(t[0], t[1], t[2], t[3]));
        bf16x8 pa1 = __builtin_bit_cast(bf16x8, make_uint4(t[4], t[5], t[6], t[7]));

        __builtin_amdgcn_s_setprio(1);
        acc = __builtin_amdgcn_mfma_f32_32x32x16_bf16(
            pa0, __builtin_bit_cast(bf16x8, v0_c), acc, 0, 0, 0);
        acc = __builtin_amdgcn_mfma_f32_32x32x16_bf16(
            pa1, __builtin_bit_cast(bf16x8, v1_c), acc, 0, 0, 0);
        __builtin_amdgcn_s_setprio(0);

        // shift pipeline (renamed by unroll, no movs)
        s_cur = s_next;
        kf_n = kf_p;
        v0_c = v0_n;
        v1_c = v1_n;
    }

    // store partials: cols 0-3 = sum p*v, col 4 = l = sum p (unnormalized)
    size_t pbase = (size_t)(js * BH + bh) * N_POS + it * 32;
    if (c < 4) {
#pragma unroll
        for (int r = 0; r < 16; ++r) {
            int row = (r & 3) + 8 * (r >> 2) + 4 * half;
            pacc[(pbase + row) * 4 + c] = acc[r];
        }
    } else if (c == 4) {
#pragma unroll
        for (int r = 0; r < 16; ++r) {
            int row = (r & 3) + 8 * (r >> 2) + 4 * half;
            pl[pbase + row] = acc[r];
        }
    }
}

// ---------------- K3: combine partials + output projection + bias -------------
// grid 1024 blocks: thread = (b, channel-group of 4, i).
__global__ __launch_bounds__(256) void out_proj(const float4* __restrict__ pacc,
                                                const float* __restrict__ pl,
                                                const float* __restrict__ w_out,
                                                const float* __restrict__ b_out,
                                                float* __restrict__ y) {
    int t = blockIdx.x * 256 + threadIdx.x;   // 4b * 16cg * 4096i
    int i  = t & 4095;
    int cg = (t >> 12) & 15;
    int b  = t >> 16;

    float of[16];
#pragma unroll
    for (int h = 0; h < 4; ++h) {
        int bh = b * 4 + h;
        float sx = 0.f, sy = 0.f, sz = 0.f, sw = 0.f, l = 0.f;
#pragma unroll
        for (int js = 0; js < JS; ++js) {
            size_t idx = (size_t)(js * BH + bh) * N_POS + i;
            float4 a = pacc[idx];
            sx += a.x; sy += a.y; sz += a.z; sw += a.w;
            l += pl[idx];
        }
        float inv = 1.0f / l;
        of[h * 4 + 0] = sx * inv;
        of[h * 4 + 1] = sy * inv;
        of[h * 4 + 2] = sz * inv;
        of[h * 4 + 3] = sw * inv;
    }

    float* yb = y + ((size_t)b * 64 + cg * 4) * N_POS + i;
#pragma unroll
    for (int cc = 0; cc < 4; ++cc) {
        int ch = cg * 4 + cc;
        const float* wr = w_out + ch * 16;     // wave-uniform row
        float s = b_out[ch];
#pragma unroll
        for (int u = 0; u < 16; ++u) s = fmaf(wr[u], of[u], s);
        yb[(size_t)cc * N_POS] = s;
    }
}

extern "C" void kernel_launch(void* const* d_in, const int* in_sizes, int n_in,
                              void* d_out, int out_size, void* d_ws, size_t ws_size,
                              hipStream_t stream) {
    const float* x     = (const float*)d_in[0];
    const float* w_qkv = (const float*)d_in[1];
    const float* w_out = (const float*)d_in[2];
    const float* b_out = (const float*)d_in[3];
    float* y = (float*)d_out;

    // workspace (bytes): qfrag 2MB | kfrag 2MB | vfrag 640KB (pad to 1MB) |
    //                    pacc JS*1MB = 4MB | pl JS*256KB = 1MB   (~10MB)
    char* w = (char*)d_ws;
    uint4*          qfrag = (uint4*)(w);
    uint4*          kfrag = (uint4*)(w + 2097152);
    unsigned short* vfrag = (unsigned short*)(w + 4194304);
    float*          pacc  = (float*)(w + 5242880);
    float*          pl    = (float*)(w + 5242880 + (size_t)JS * 1048576);

    qkv_pack<<<3 * 256, 256, 0, stream>>>(x, w_qkv, qfrag, kfrag, vfrag);
    attn_mfma<<<BH * 32 * JS, 256, 0, stream>>>(qfrag, kfrag, (const uint4*)vfrag,
                                                pacc, pl);
    out_proj<<<1024, 256, 0, stream>>>((const float4*)pacc, pl, w_out, b_out, y);
}

// Round 18
// 51.417 us; speedup vs baseline: 2.4903x; 2.4903x over previous
//
#include <hip/hip_runtime.h>
#include <hip/hip_bf16.h>

#define N_POS 4096
#define BH 16  // B * HEADS
#define JS 4   // j-slices: with 2 i-tiles/wave -> 1024 blocks = 4/CU, one fill

typedef float f32x16 __attribute__((ext_vector_type(16)));
typedef short bf16x8 __attribute__((ext_vector_type(8)));

// fold attn scale (dim^-0.5 = 0.5) and log2(e) into q at pack time
#define QSCALE (0.5f * 1.44269504088896f)

__device__ __forceinline__ float fexp2(float x) {
#if __has_builtin(__builtin_amdgcn_exp2f)
    return __builtin_amdgcn_exp2f(x);
#else
    return exp2f(x);
#endif
}

__device__ __forceinline__ unsigned int bfbits(float f) {
    __hip_bfloat16 h = __float2bfloat16(f);
    return (unsigned int)*reinterpret_cast<unsigned short*>(&h);
}
__device__ __forceinline__ float bff32(unsigned int u) {
    unsigned int w = u << 16;
    float f;
    __builtin_memcpy(&f, &w, 4);
    return f;
}
__device__ __forceinline__ unsigned int pk2(unsigned int lo, unsigned int hi) {
    return lo | (hi << 16);
}

// ---------------- K1: qkv projection + MFMA fragment packing ----------------
// grid = 3 roles x 16 bh x 16 chunks = 768 blocks.
//  qfrag[bh][it][half][i&31]  : B-frag for QK  (half0=[qhi,qlo], half1=[qhi,0])
//  kfrag[bh][jt][half][j&31]  : A-frag for QK  (half0=[khi,khi], half1=[klo,0])
//   -> one 32x32x16 MFMA computes qhi*khi + qlo*khi + qhi*klo  (compensated dot)
//  vfrag[bh][step][vh][col][8]: B-frag for PV, col4 = ones (free l = sum(p))
__global__ __launch_bounds__(256) void qkv_pack(const float* __restrict__ x,
                                                const float* __restrict__ w_qkv,
                                                uint4* __restrict__ qfrag,
                                                uint4* __restrict__ kfrag,
                                                unsigned short* __restrict__ vfrag) {
    int blk = blockIdx.x;
    int role = blk >> 8;         // 0=q 1=k 2=v
    int bh = (blk >> 4) & 15;
    int chunk = blk & 15;
    int b = bh >> 2, h = bh & 3;
    int i = chunk * 256 + threadIdx.x;

    const float* xb = x + ((size_t)b * 64) * N_POS + i;
    const float* wr = w_qkv + (role * 16 + h * 4) * 64;   // wave-uniform rows

    float a[4] = {0, 0, 0, 0};
#pragma unroll 8
    for (int c = 0; c < 64; ++c) {
        float xv = xb[(size_t)c * N_POS];
#pragma unroll
        for (int d = 0; d < 4; ++d)
            a[d] = fmaf(wr[d * 64 + c], xv, a[d]);
    }

    int it = i >> 5, il = i & 31;
    size_t base = ((size_t)(bh * 128 + it) * 2) * 32 + il;

    if (role == 0) {
        unsigned int qh[4], ql[4];
#pragma unroll
        for (int d = 0; d < 4; ++d) {
            float qs = a[d] * QSCALE;
            qh[d] = bfbits(qs);
            ql[d] = bfbits(qs - bff32(qh[d]));
        }
        qfrag[base]      = make_uint4(pk2(qh[0], qh[1]), pk2(qh[2], qh[3]),
                                      pk2(ql[0], ql[1]), pk2(ql[2], ql[3]));
        qfrag[base + 32] = make_uint4(pk2(qh[0], qh[1]), pk2(qh[2], qh[3]), 0u, 0u);
    } else if (role == 1) {
        unsigned int kh[4], kl[4];
#pragma unroll
        for (int d = 0; d < 4; ++d) {
            kh[d] = bfbits(a[d]);
            kl[d] = bfbits(a[d] - bff32(kh[d]));
        }
        kfrag[base]      = make_uint4(pk2(kh[0], kh[1]), pk2(kh[2], kh[3]),
                                      pk2(kh[0], kh[1]), pk2(kh[2], kh[3]));
        kfrag[base + 32] = make_uint4(pk2(kl[0], kl[1]), pk2(kl[2], kl[3]), 0u, 0u);
    } else {
        // v transpose-pack: element (j&7) of entry [step=j>>4][vh=(j>>3)&1][col=d]
        int step = i >> 4, vh = (i >> 3) & 1, e = i & 7;
        size_t ventry = ((size_t)(bh * 256 + step) * 2 + vh) * 5;
#pragma unroll
        for (int d = 0; d < 4; ++d)
            vfrag[(ventry + d) * 8 + e] = (unsigned short)bfbits(a[d]);
        if (e == 0)  // ones column -> PV MFMA also produces l = sum_j p
            reinterpret_cast<uint4*>(vfrag)[ventry + 4] =
                make_uint4(0x3F803F80u, 0x3F803F80u, 0x3F803F80u, 0x3F803F80u);
    }
}

// ---------------- K2: MFMA flash attention partials, 2 i-tiles/wave ----------
// wave = TWO adjacent 32-row i-tiles x one j-slice (1024 j, JT=32).
// K/V loads + addressing shared between the tiles (per-tile mem ops halved);
// two independent QK->softmax->PV chains give intra-wave ILP the compiler
// cannot collapse. Depth-2 K / depth-1 V prefetch. All-trans exp (poly split
// measured worse, r13). lb(256,4): (256,8) starves the live set (r17: VGPR 32,
// 3.7x refetch, 122us — permanently dead).
__global__ __launch_bounds__(256, 4) void attn_mfma(const uint4* __restrict__ qfrag,
                                                    const uint4* __restrict__ kfrag,
                                                    const uint4* __restrict__ vfrag,
                                                    float* __restrict__ pacc,
                                                    float* __restrict__ pl) {
    constexpr int JT = 128 / JS;                 // 32 j-tiles per wave
    int wave = threadIdx.x >> 6;
    int lane = threadIdx.x & 63;
    int half = lane >> 5, c = lane & 31;
    int blk = blockIdx.x;                        // 16 bh * 16 itg * JS = 1024
    int js = blk & (JS - 1);
    int itg = (blk / JS) & 15;
    int bh = blk / (JS * 16);
    int it0 = itg * 8 + wave * 2;                // two adjacent i-tiles
    int it1 = it0 + 1;

    bf16x8 qfA = __builtin_bit_cast(bf16x8,
        qfrag[((size_t)(bh * 128 + it0) * 2 + half) * 32 + c]);
    bf16x8 qfB = __builtin_bit_cast(bf16x8,
        qfrag[((size_t)(bh * 128 + it1) * 2 + half) * 32 + c]);

    const uint4* kp = kfrag + (size_t)bh * 128 * 64 + (size_t)js * JT * 64
                    + (size_t)half * 32 + c;
    int vcol = c < 4 ? c : 4;    // cols >4 read the ones column (result ignored)
    const uint4* vp = vfrag + (size_t)bh * 2560 + (size_t)js * JT * 20
                    + half * 5 + vcol;

    f32x16 accA, accB, zc;
#pragma unroll
    for (int r = 0; r < 16; ++r) { accA[r] = 0.f; accB[r] = 0.f; zc[r] = 0.f; }

    uint4 kf_c = kp[0];
    uint4 kf_n = kp[64];
    uint4 v0_c = vp[0], v1_c = vp[10];

#pragma unroll 2
    for (int jj = 0; jj < JT; ++jj) {
        int j2 = (jj + 2 < JT) ? jj + 2 : JT - 1;
        int j1 = (jj + 1 < JT) ? jj + 1 : JT - 1;
        uint4 kf_p = kp[j2 * 64];
        uint4 v0_n = vp[(2 * j1) * 10];
        uint4 v1_n = vp[(2 * j1 + 1) * 10];

        // two independent QK MFMAs off the SAME kf (shared load)
        bf16x8 kf = __builtin_bit_cast(bf16x8, kf_c);
        f32x16 sA = __builtin_amdgcn_mfma_f32_32x32x16_bf16(kf, qfA, zc, 0, 0, 0);
        f32x16 sB = __builtin_amdgcn_mfma_f32_32x32x16_bf16(kf, qfB, zc, 0, 0, 0);

        bf16x8 v0 = __builtin_bit_cast(bf16x8, v0_c);
        bf16x8 v1 = __builtin_bit_cast(bf16x8, v1_c);

        // ---- tile A: softmax + PV (B's QK MFMA completes underneath) ----
        {
            unsigned int t[8];
#pragma unroll
            for (int eo = 0; eo < 8; ++eo) {
                float plo = fexp2(sA[2 * eo]);
                float phi = fexp2(sA[2 * eo + 1]);
                unsigned int r_;
                asm("v_cvt_pk_bf16_f32 %0, %1, %2" : "=v"(r_) : "v"(plo), "v"(phi));
                t[eo] = r_;
            }
            asm("v_permlane32_swap_b32 %0, %1" : "+v"(t[0]), "+v"(t[2]));
            asm("v_permlane32_swap_b32 %0, %1" : "+v"(t[1]), "+v"(t[3]));
            asm("v_permlane32_swap_b32 %0, %1" : "+v"(t[4]), "+v"(t[6]));
            asm("v_permlane32_swap_b32 %0, %1" : "+v"(t[5]), "+v"(t[7]));
            bf16x8 pa0 = __builtin_bit_cast(bf16x8, make_uint4(t[0], t[1], t[2], t[3]));
            bf16x8 pa1 = __builtin_bit_cast(bf16x8, make_uint4(t[4], t[5], t[6], t[7]));
            __builtin_amdgcn_s_setprio(1);
            accA = __builtin_amdgcn_mfma_f32_32x32x16_bf16(pa0, v0, accA, 0, 0, 0);
            accA = __builtin_amdgcn_mfma_f32_32x32x16_bf16(pa1, v1, accA, 0, 0, 0);
            __builtin_amdgcn_s_setprio(0);
        }
        // ---- tile B: softmax + PV (A's PV MFMAs complete underneath) ----
        {
            unsigned int t[8];
#pragma unroll
            for (int eo = 0; eo < 8; ++eo) {
                float plo = fexp2(sB[2 * eo]);
                float phi = fexp2(sB[2 * eo + 1]);
                unsigned int r_;
                asm("v_cvt_pk_bf16_f32 %0, %1, %2" : "=v"(r_) : "v"(plo), "v"(phi));
                t[eo] = r_;
            }
            asm("v_permlane32_swap_b32 %0, %1" : "+v"(t[0]), "+v"(t[2]));
            asm("v_permlane32_swap_b32 %0, %1" : "+v"(t[1]), "+v"(t[3]));
            asm("v_permlane32_swap_b32 %0, %1" : "+v"(t[4]), "+v"(t[6]));
            asm("v_permlane32_swap_b32 %0, %1" : "+v"(t[5]), "+v"(t[7]));
            bf16x8 pa0 = __builtin_bit_cast(bf16x8, make_uint4(t[0], t[1], t[2], t[3]));
            bf16x8 pa1 = __builtin_bit_cast(bf16x8, make_uint4(t[4], t[5], t[6], t[7]));
            __builtin_amdgcn_s_setprio(1);
            accB = __builtin_amdgcn_mfma_f32_32x32x16_bf16(pa0, v0, accB, 0, 0, 0);
            accB = __builtin_amdgcn_mfma_f32_32x32x16_bf16(pa1, v1, accB, 0, 0, 0);
            __builtin_amdgcn_s_setprio(0);
        }

        kf_c = kf_n; kf_n = kf_p;
        v0_c = v0_n; v1_c = v1_n;
    }

    // store partials: cols 0-3 = sum p*v, col 4 = l = sum p (unnormalized)
    size_t pbase0 = (size_t)(js * BH + bh) * N_POS + it0 * 32;
    size_t pbase1 = pbase0 + 32;
    if (c < 4) {
#pragma unroll
        for (int r = 0; r < 16; ++r) {
            int row = (r & 3) + 8 * (r >> 2) + 4 * half;
            pacc[(pbase0 + row) * 4 + c] = accA[r];
            pacc[(pbase1 + row) * 4 + c] = accB[r];
        }
    } else if (c == 4) {
#pragma unroll
        for (int r = 0; r < 16; ++r) {
            int row = (r & 3) + 8 * (r >> 2) + 4 * half;
            pl[pbase0 + row] = accA[r];
            pl[pbase1 + row] = accB[r];
        }
    }
}

// ---------------- K3: combine partials + output projection + bias -------------
// grid 1024 blocks: thread = (b, channel-group of 4, i).
__global__ __launch_bounds__(256) void out_proj(const float4* __restrict__ pacc,
                                                const float* __restrict__ pl,
                                                const float* __restrict__ w_out,
                                                const float* __restrict__ b_out,
                                                float* __restrict__ y) {
    int t = blockIdx.x * 256 + threadIdx.x;   // 4b * 16cg * 4096i
    int i  = t & 4095;
    int cg = (t >> 12) & 15;
    int b  = t >> 16;

    float of[16];
#pragma unroll
    for (int h = 0; h < 4; ++h) {
        int bh = b * 4 + h;
        float sx = 0.f, sy = 0.f, sz = 0.f, sw = 0.f, l = 0.f;
#pragma unroll
        for (int js = 0; js < JS; ++js) {
            size_t idx = (size_t)(js * BH + bh) * N_POS + i;
            float4 a = pacc[idx];
            sx += a.x; sy += a.y; sz += a.z; sw += a.w;
            l += pl[idx];
        }
        float inv = 1.0f / l;
        of[h * 4 + 0] = sx * inv;
        of[h * 4 + 1] = sy * inv;
        of[h * 4 + 2] = sz * inv;
        of[h * 4 + 3] = sw * inv;
    }

    float* yb = y + ((size_t)b * 64 + cg * 4) * N_POS + i;
#pragma unroll
    for (int cc = 0; cc < 4; ++cc) {
        int ch = cg * 4 + cc;
        const float* wr = w_out + ch * 16;     // wave-uniform row
        float s = b_out[ch];
#pragma unroll
        for (int u = 0; u < 16; ++u) s = fmaf(wr[u], of[u], s);
        yb[(size_t)cc * N_POS] = s;
    }
}

extern "C" void kernel_launch(void* const* d_in, const int* in_sizes, int n_in,
                              void* d_out, int out_size, void* d_ws, size_t ws_size,
                              hipStream_t stream) {
    const float* x     = (const float*)d_in[0];
    const float* w_qkv = (const float*)d_in[1];
    const float* w_out = (const float*)d_in[2];
    const float* b_out = (const float*)d_in[3];
    float* y = (float*)d_out;

    // workspace (bytes): qfrag 2MB | kfrag 2MB | vfrag 640KB (pad to 1MB) |
    //                    pacc JS*1MB = 4MB | pl JS*256KB = 1MB   (~10MB)
    char* w = (char*)d_ws;
    uint4*          qfrag = (uint4*)(w);
    uint4*          kfrag = (uint4*)(w + 2097152);
    unsigned short* vfrag = (unsigned short*)(w + 4194304);
    float*          pacc  = (float*)(w + 5242880);
    float*          pl    = (float*)(w + 5242880 + (size_t)JS * 1048576);

    qkv_pack<<<3 * 256, 256, 0, stream>>>(x, w_qkv, qfrag, kfrag, vfrag);
    attn_mfma<<<BH * 16 * JS, 256, 0, stream>>>(qfrag, kfrag, (const uint4*)vfrag,
                                                pacc, pl);
    out_proj<<<1024, 256, 0, stream>>>((const float4*)pacc, pl, w_out, b_out, y);
}